// Round 10
// baseline (384.089 us; speedup 1.0000x reference)
//
#include <hip/hip_runtime.h>

typedef short bf16x8 __attribute__((ext_vector_type(8)));
typedef float f32x4 __attribute__((ext_vector_type(4)));
typedef unsigned int u32;

#define NT 32
#define NB 4096
#define ND 32
#define NW 64

// Dopri5 tableau
#define A31 ((float)(3.0/40.0))
#define A32 ((float)(9.0/40.0))
#define A41 ((float)(44.0/45.0))
#define A42 ((float)(-56.0/15.0))
#define A43 ((float)(32.0/9.0))
#define A51 ((float)(19372.0/6561.0))
#define A52 ((float)(-25360.0/2187.0))
#define A53 ((float)(64448.0/6561.0))
#define A54 ((float)(-212.0/729.0))
#define A61 ((float)(9017.0/3168.0))
#define A62 ((float)(-355.0/33.0))
#define A63 ((float)(46732.0/5247.0))
#define A64 ((float)(49.0/176.0))
#define A65 ((float)(-5103.0/18656.0))
#define BB1 ((float)(35.0/384.0))
#define BB3 ((float)(500.0/1113.0))
#define BB4 ((float)(125.0/192.0))
#define BB5 ((float)(-2187.0/6784.0))
#define BB6 ((float)(11.0/84.0))

// Single-instruction RNE pack: D.lo = bf16(a), D.hi = bf16(b)
__device__ __forceinline__ u32 pk(float a, float b) {
    u32 r;
    asm("v_cvt_pk_bf16_f32 %0, %1, %2" : "=v"(r) : "v"(a), "v"(b));
    return r;
}
// Softplus — R7's proven implementation (OCML fast intrinsics, hazard-safe).
__device__ __forceinline__ float sp(float x) {
    return __logf(1.0f + __expf(x));
}
// LDS-only barrier: skip __syncthreads' vmcnt(0) drain of async out-stores.
__device__ __forceinline__ void lds_barrier() {
    asm volatile("s_waitcnt lgkmcnt(0)\n\ts_barrier" ::: "memory");
}
__device__ __forceinline__ bf16x8 mk_afrag(const float* p) {
    union { u32 u[4]; bf16x8 v; } r;
    r.u[0] = pk(p[0], p[1]); r.u[1] = pk(p[2], p[3]);
    r.u[2] = pk(p[4], p[5]); r.u[3] = pk(p[6], p[7]);
    return r.v;
}

// BISECT: R8's two-group structure + R7's exact per-group math (no weight
// folding). If this passes, the R8/R9 NaN was the exp2/log2 folding path;
// if it NaNs, the two-group structure races.
//
// Structure (32 rows/block = TWO independent 16-row groups, 4 waves,
// 2 barriers/eval-PAIR):
//  - L1/L2: wave w owns hidden m-tile w; h1/h2 via swizzled LDS, one
//    buffer per group; groups' work interleaves in each barrier segment.
//  - L3: permuted m-tiles (R7), redundant on all waves: lane (q,n)
//    accumulates y-dims {8q..8q+7} = next B-frag k-range; RK state
//    register-resident, NO y-exchange.

__global__ __launch_bounds__(256, 1)
void node_kernel(const float* __restrict__ ts, const float* __restrict__ y0,
                 const float* __restrict__ W1, const float* __restrict__ b1,
                 const float* __restrict__ W2, const float* __restrict__ b2,
                 const float* __restrict__ W3, const float* __restrict__ b3,
                 float* __restrict__ out)
{
    __shared__ __align__(16) u32 h1ds[2][16 * 32];
    __shared__ __align__(16) u32 h2ds[2][16 * 32];
    __shared__ float hsl[NT];

    const int tid  = threadIdx.x;
    const int w    = tid >> 6;          // wave 0..3
    const int lane = tid & 63;
    const int n    = lane & 15;         // batch col / A-row slot
    const int q    = lane >> 4;         // MFMA quad
    const int swz  = (n & 7) << 2;
    const int row0 = blockIdx.x * 32;   // two groups: rows row0+16g+n

    if (tid < NT - 1) hsl[tid] = (ts[tid + 1] - ts[tid]) * 0.5f;  // K=2

    // ---- L1/L2 weights (shared across groups): wave w owns m-tile w ----
    bf16x8 a1   = mk_afrag(W1 + (w * 16 + n) * ND + q * 8);
    bf16x8 a2lo = mk_afrag(W2 + (w * 16 + n) * NW + q * 8);
    bf16x8 a2hi = mk_afrag(W2 + (w * 16 + n) * NW + 32 + q * 8);
    f32x4 bs1 = *(const f32x4*)(b1 + w * 16 + q * 4);
    f32x4 bs2 = *(const f32x4*)(b2 + w * 16 + q * 4);

    // ---- L3 permuted A-frags (all waves): row g(t) = 8*(n>>2)+4t+(n&3) ----
    const int gb = 8 * (n >> 2) + (n & 3);
    bf16x8 a3[2][2];
    #pragma unroll
    for (int t = 0; t < 2; ++t) {
        a3[t][0] = mk_afrag(W3 + (gb + 4 * t) * NW + q * 8);
        a3[t][1] = mk_afrag(W3 + (gb + 4 * t) * NW + 32 + q * 8);
    }
    f32x4 bs3[2];
    bs3[0] = *(const f32x4*)(b3 + 8 * q);
    bs3[1] = *(const f32x4*)(b3 + 8 * q + 4);

    // ---- RK state: lane (q,n) owns y[row0+16g+n][8q..8q+7], g=0,1 ----
    f32x4 yA[2], yB[2];
    #pragma unroll
    for (int g = 0; g < 2; ++g) {
        yA[g] = *(const f32x4*)(y0 + (size_t)(row0 + 16 * g + n) * ND + 8 * q);
        yB[g] = *(const f32x4*)(y0 + (size_t)(row0 + 16 * g + n) * ND + 8 * q + 4);
        if (w == 0) {
            *(f32x4*)(out + (size_t)(row0 + 16 * g + n) * ND + 8 * q)     = yA[g];
            *(f32x4*)(out + (size_t)(row0 + 16 * g + n) * ND + 8 * q + 4) = yB[g];
        }
    }
    __syncthreads();    // hsl visible

    auto mkby = [&](f32x4 sA, f32x4 sB) -> bf16x8 {
        union { u32 u[4]; bf16x8 v; } r;
        r.u[0] = pk(sA[0], sA[1]); r.u[1] = pk(sA[2], sA[3]);
        r.u[2] = pk(sB[0], sB[1]); r.u[3] = pk(sB[2], sB[3]);
        return r.v;
    };

    auto evalf = [&](bf16x8 (&by)[2], f32x4 (&kA)[2], f32x4 (&kB)[2]) {
        f32x4 u[2];
        #pragma unroll
        for (int g = 0; g < 2; ++g)
            u[g] = __builtin_amdgcn_mfma_f32_16x16x32_bf16(a1, by[g], bs1, 0, 0, 0);
        #pragma unroll
        for (int g = 0; g < 2; ++g) {
            uint2 p;
            p.x = pk(sp(u[g][0]), sp(u[g][1])); p.y = pk(sp(u[g][2]), sp(u[g][3]));
            *(uint2*)&h1ds[g][n * 32 + ((w * 8 + q * 2) ^ swz)] = p;
        }
        lds_barrier();                                       // B1: h1 ready
        bf16x8 bh0[2], bh1[2];
        #pragma unroll
        for (int g = 0; g < 2; ++g) {
            bh0[g] = *(const bf16x8*)&h1ds[g][n * 32 + ((q * 4) ^ swz)];
            bh1[g] = *(const bf16x8*)&h1ds[g][n * 32 + ((16 + q * 4) ^ swz)];
        }
        f32x4 v[2];
        #pragma unroll
        for (int g = 0; g < 2; ++g) {
            f32x4 t = __builtin_amdgcn_mfma_f32_16x16x32_bf16(a2lo, bh0[g], bs2, 0, 0, 0);
            v[g]    = __builtin_amdgcn_mfma_f32_16x16x32_bf16(a2hi, bh1[g], t, 0, 0, 0);
        }
        #pragma unroll
        for (int g = 0; g < 2; ++g) {
            uint2 p;
            p.x = pk(sp(v[g][0]), sp(v[g][1])); p.y = pk(sp(v[g][2]), sp(v[g][3]));
            *(uint2*)&h2ds[g][n * 32 + ((w * 8 + q * 2) ^ swz)] = p;
        }
        lds_barrier();                                       // B2: h2 ready
        bf16x8 c0[2], c1[2];
        #pragma unroll
        for (int g = 0; g < 2; ++g) {
            c0[g] = *(const bf16x8*)&h2ds[g][n * 32 + ((q * 4) ^ swz)];
            c1[g] = *(const bf16x8*)&h2ds[g][n * 32 + ((16 + q * 4) ^ swz)];
        }
        #pragma unroll
        for (int g = 0; g < 2; ++g) {
            f32x4 tA = __builtin_amdgcn_mfma_f32_16x16x32_bf16(a3[0][0], c0[g], bs3[0], 0, 0, 0);
            f32x4 tB = __builtin_amdgcn_mfma_f32_16x16x32_bf16(a3[1][0], c0[g], bs3[1], 0, 0, 0);
            kA[g] = __builtin_amdgcn_mfma_f32_16x16x32_bf16(a3[0][1], c1[g], tA, 0, 0, 0);
            kB[g] = __builtin_amdgcn_mfma_f32_16x16x32_bf16(a3[1][1], c1[g], tB, 0, 0, 0);
        }
    };

    bf16x8 by[2];
    #pragma unroll
    for (int g = 0; g < 2; ++g) by[g] = mkby(yA[g], yB[g]);

    #pragma unroll 1
    for (int iv = 0; iv < NT - 1; ++iv) {
        const float hs = hsl[iv];
        #pragma unroll 1
        for (int sub = 0; sub < 2; ++sub) {
            f32x4 k1A[2], k1B[2], k2A[2], k2B[2], k3A[2], k3B[2];
            f32x4 k4A[2], k4B[2], k5A[2], k5B[2], k6A[2], k6B[2];
            evalf(by, k1A, k1B);
            #pragma unroll
            for (int g = 0; g < 2; ++g)
                by[g] = mkby(yA[g] + hs * (0.2f * k1A[g]),
                             yB[g] + hs * (0.2f * k1B[g]));
            evalf(by, k2A, k2B);
            #pragma unroll
            for (int g = 0; g < 2; ++g)
                by[g] = mkby(yA[g] + hs * (A31 * k1A[g] + A32 * k2A[g]),
                             yB[g] + hs * (A31 * k1B[g] + A32 * k2B[g]));
            evalf(by, k3A, k3B);
            #pragma unroll
            for (int g = 0; g < 2; ++g)
                by[g] = mkby(yA[g] + hs * (A41 * k1A[g] + A42 * k2A[g] + A43 * k3A[g]),
                             yB[g] + hs * (A41 * k1B[g] + A42 * k2B[g] + A43 * k3B[g]));
            evalf(by, k4A, k4B);
            #pragma unroll
            for (int g = 0; g < 2; ++g)
                by[g] = mkby(yA[g] + hs * (A51 * k1A[g] + A52 * k2A[g] + A53 * k3A[g] + A54 * k4A[g]),
                             yB[g] + hs * (A51 * k1B[g] + A52 * k2B[g] + A53 * k3B[g] + A54 * k4B[g]));
            evalf(by, k5A, k5B);
            #pragma unroll
            for (int g = 0; g < 2; ++g)
                by[g] = mkby(yA[g] + hs * (A61 * k1A[g] + A62 * k2A[g] + A63 * k3A[g] + A64 * k4A[g] + A65 * k5A[g]),
                             yB[g] + hs * (A61 * k1B[g] + A62 * k2B[g] + A63 * k3B[g] + A64 * k4B[g] + A65 * k5B[g]));
            evalf(by, k6A, k6B);
            #pragma unroll
            for (int g = 0; g < 2; ++g) {
                yA[g] = yA[g] + hs * (BB1 * k1A[g] + BB3 * k3A[g] + BB4 * k4A[g] + BB5 * k5A[g] + BB6 * k6A[g]);
                yB[g] = yB[g] + hs * (BB1 * k1B[g] + BB3 * k3B[g] + BB4 * k4B[g] + BB5 * k5B[g] + BB6 * k6B[g]);
                by[g] = mkby(yA[g], yB[g]);
            }
        }
        if (w == 0) {
            #pragma unroll
            for (int g = 0; g < 2; ++g) {
                *(f32x4*)(out + ((size_t)(iv + 1) * NB + row0 + 16 * g + n) * ND + 8 * q)     = yA[g];
                *(f32x4*)(out + ((size_t)(iv + 1) * NB + row0 + 16 * g + n) * ND + 8 * q + 4) = yB[g];
            }
        }
    }

    if (blockIdx.x == 0 && tid == 0) {
        out[(size_t)NT * NB * ND] = 62.0f;                   // num_steps = (T-1)*K
    }
}

extern "C" void kernel_launch(void* const* d_in, const int* in_sizes, int n_in,
                              void* d_out, int out_size, void* d_ws, size_t ws_size,
                              hipStream_t stream) {
    const float* ts = (const float*)d_in[0];
    const float* y0 = (const float*)d_in[1];
    const float* W1 = (const float*)d_in[2];
    const float* b1 = (const float*)d_in[3];
    const float* W2 = (const float*)d_in[4];
    const float* b2 = (const float*)d_in[5];
    const float* W3 = (const float*)d_in[6];
    const float* b3 = (const float*)d_in[7];
    float* out = (float*)d_out;

    node_kernel<<<dim3(NB / 32), dim3(256), 0, stream>>>(ts, y0, W1, b1, W2, b2, W3, b3, out);
}